// Round 1
// baseline (1193.757 us; speedup 1.0000x reference)
//
#include <hip/hip_runtime.h>

// Problem constants (fixed by reference)
#define N_SRC   100000
#define N_DSTC  50000
#define N_EDGES 1000000
#define DIM     64
#define NCLS    64

// ws layout (floats):
//   [0, N_DSTC*64)            ysum
//   [+N_DSTC*64, +N_DSTC)     deg
//   [.., +64)                 colsum
//   [.., +1)                  regacc

// ---------------------------------------------------------------------------
// Kernel 1: edge gather + atomic scatter.
// 16 threads per edge; each thread handles 4 consecutive features (float4 load,
// 4 scalar f32 atomics). Consecutive 16 lanes read one contiguous 256B x-row.
__global__ __launch_bounds__(256) void edge_scatter(
    const float* __restrict__ x,
    const int*   __restrict__ src,
    const int*   __restrict__ dst,
    float* __restrict__ ysum,
    float* __restrict__ deg) {
  long long t = (long long)blockIdx.x * blockDim.x + threadIdx.x;
  int e = (int)(t >> 4);
  int q = (int)(t & 15);
  if (e >= N_EDGES) return;
  int s  = src[e];
  int d0 = dst[e];
  const float4 v = reinterpret_cast<const float4*>(x)[(long long)s * 16 + q];
  float* yp = ysum + (long long)d0 * DIM + q * 4;
  atomicAdd(yp + 0, v.x);
  atomicAdd(yp + 1, v.y);
  atomicAdd(yp + 2, v.z);
  atomicAdd(yp + 3, v.w);
  if (q == 0) atomicAdd(deg + d0, 1.0f);
}

// ---------------------------------------------------------------------------
// Kernel 2: y_mean + h = [x_dst, y_mean] @ W^T + b, and column sums of y_mean.
// One wave per dst row; lane c computes h[r][c]. W^T staged in LDS with +1-pad
// (row stride 65 -> 2 lanes/bank on column reads, free). Feature row staged in
// per-wave LDS; inner-loop reads of feat[wv][k] are same-address broadcasts.
__global__ __launch_bounds__(256) void fuse_h(
    const float* __restrict__ x,
    const float* __restrict__ Ww,   // [64][128]
    const float* __restrict__ Wb,   // [64]
    const float* __restrict__ ysum,
    const float* __restrict__ deg,
    float* __restrict__ h,
    float* __restrict__ colsum) {
  __shared__ float Wt[128][65];   // Wt[k][c] = Ww[c*128+k]
  __shared__ float feat[4][128];

  const int tid = threadIdx.x;
  for (int idx = tid; idx < NCLS * 2 * DIM; idx += 256) {
    int c = idx >> 7;         // class
    int k = idx & 127;        // feature
    Wt[k][c] = Ww[idx];       // coalesced read, spread LDS write banks
  }
  __syncthreads();

  const int wv   = tid >> 6;
  const int lane = tid & 63;
  const int waveId     = blockIdx.x * 4 + wv;
  const int totalWaves = gridDim.x * 4;
  const int nIter = (N_DSTC + totalWaves - 1) / totalWaves;

  float colacc = 0.0f;
  const float bias = Wb[lane];

  for (int it = 0; it < nIter; ++it) {
    int  r   = waveId + it * totalWaves;
    bool act = (r < N_DSTC);
    if (act) {
      float xv  = x[(long long)r * DIM + lane];
      float sum = ysum[(long long)r * DIM + lane];
      float dg  = deg[r];                       // same addr all lanes: broadcast
      float ym  = sum / fmaxf(dg, 1.0f);
      colacc += ym;                             // lane == column
      feat[wv][lane]       = xv;
      feat[wv][DIM + lane] = ym;
    }
    __syncthreads();
    if (act) {
      float acc = bias;
      #pragma unroll 16
      for (int k = 0; k < 2 * DIM; ++k)
        acc = fmaf(feat[wv][k], Wt[k][lane], acc);
      h[(long long)r * NCLS + lane] = acc;
    }
    __syncthreads();
  }
  atomicAdd(&colsum[lane], colacc);
}

// ---------------------------------------------------------------------------
// Kernel 3: reg partial sums. One wave per x row, lane j owns column j.
__global__ __launch_bounds__(256) void reg_kernel(
    const float* __restrict__ x,
    const float* __restrict__ u_sum,
    const float* __restrict__ colsum,
    float* __restrict__ regacc) {
  const int tid  = threadIdx.x;
  const int wv   = tid >> 6;
  const int lane = tid & 63;
  const int waveId     = blockIdx.x * 4 + wv;
  const int totalWaves = gridDim.x * 4;
  const float inv_nd = 1.0f / (float)N_DSTC;
  const float mx = colsum[lane] * inv_nd;   // mean_x[lane]

  float acc = 0.0f;
  for (int r = waveId; r < N_SRC; r += totalWaves) {
    float u  = u_sum[r] * inv_nd;           // same addr all lanes: broadcast
    float xv = x[(long long)r * DIM + lane];
    float d  = fmaf(u, xv, -mx);
    acc = fmaf(d, d, acc);
  }
  #pragma unroll
  for (int off = 32; off > 0; off >>= 1)
    acc += __shfl_down(acc, off, 64);
  if (lane == 0) atomicAdd(regacc, acc);
}

// ---------------------------------------------------------------------------
__global__ void finalize(const float* __restrict__ regacc,
                         float* __restrict__ out_scalar) {
  out_scalar[0] = regacc[0] * (1.0f / ((float)N_SRC * (float)NCLS));
}

// ---------------------------------------------------------------------------
extern "C" void kernel_launch(void* const* d_in, const int* in_sizes, int n_in,
                              void* d_out, int out_size, void* d_ws, size_t ws_size,
                              hipStream_t stream) {
  const float* x     = (const float*)d_in[0];
  // d_in[1] = w : dead (only ones_like(w) is used)
  const float* u_sum = (const float*)d_in[2];
  const float* Ww    = (const float*)d_in[3];
  const float* Wb    = (const float*)d_in[4];
  const int*   src   = (const int*)d_in[5];
  const int*   dst   = (const int*)d_in[6];
  // d_in[7] = n_dst scalar; compile-time N_DSTC

  float* out    = (float*)d_out;
  float* ws     = (float*)d_ws;
  float* ysum   = ws;
  float* deg    = ysum + (size_t)N_DSTC * DIM;
  float* colsum = deg + N_DSTC;
  float* regacc = colsum + 64;

  size_t zero_bytes = ((size_t)N_DSTC * DIM + N_DSTC + 64 + 1) * sizeof(float);
  hipMemsetAsync(d_ws, 0, zero_bytes, stream);

  // 16 threads/edge
  int escatter_blocks = (N_EDGES * 16) / 256;  // 62500
  edge_scatter<<<escatter_blocks, 256, 0, stream>>>(x, src, dst, ysum, deg);

  fuse_h<<<1024, 256, 0, stream>>>(x, Ww, Wb, ysum, deg, out, colsum);

  reg_kernel<<<2048, 256, 0, stream>>>(x, u_sum, colsum, regacc);

  finalize<<<1, 1, 0, stream>>>(regacc, out + (size_t)N_DSTC * NCLS);
}

// Round 4
// 511.207 us; speedup vs baseline: 2.3352x; 2.3352x over previous
//
#include <hip/hip_runtime.h>

// Problem constants (fixed by reference)
#define N_SRC   100000
#define N_DSTC  50000
#define N_EDGES 1000000
#define DIM     64
#define NCLS    64

// ws layout (4-byte elements):
//   hist       [0, 50000)          int   (zeroed each launch)
//   colsum     [50000, 50064)      float (zeroed)
//   regacc     [50064, 50065)      float (zeroed)
//   cursor     [50065, 100065)     int   (written by scan, mutated by reorder)
//   sorted_src [100065, 1100065)   int   (fully written by reorder)

// ---------------------------------------------------------------------------
// K1: histogram of dst (int atomics; ~20 edges/bin avg -> low contention)
__global__ __launch_bounds__(256) void hist_kernel(
    const int* __restrict__ dst, int* __restrict__ hist) {
  int e = blockIdx.x * blockDim.x + threadIdx.x;
  if (e < N_EDGES) atomicAdd(&hist[dst[e]], 1);
}

// ---------------------------------------------------------------------------
// K2: single-block exclusive scan -> cursor (start offsets).
// Ping-pong double-buffered scan: each step reads only `cur`, writes only own
// slot of `nxt` -> no read/write hazard by construction.
__global__ __launch_bounds__(1024) void scan_kernel(
    const int* __restrict__ hist, int* __restrict__ cursor) {
  __shared__ int bufA[1024];
  __shared__ int bufB[1024];
  const int t = threadIdx.x;
  const int chunk = (N_DSTC + 1023) / 1024;  // 49
  int beg = t * chunk;       if (beg > N_DSTC) beg = N_DSTC;
  int end = beg + chunk;     if (end > N_DSTC) end = N_DSTC;

  int s = 0;
  for (int i = beg; i < end; ++i) s += hist[i];
  bufA[t] = s;
  __syncthreads();

  int* cur = bufA;
  int* nxt = bufB;
  for (int off = 1; off < 1024; off <<= 1) {
    int v = cur[t] + ((t >= off) ? cur[t - off] : 0);
    nxt[t] = v;
    __syncthreads();
    int* tmp = cur; cur = nxt; nxt = tmp;
  }
  // cur[t] = inclusive scan of per-thread partials
  int run = (t > 0) ? cur[t - 1] : 0;
  for (int i = beg; i < end; ++i) {
    cursor[i] = run;
    run += hist[i];
  }
}

// ---------------------------------------------------------------------------
// K3: counting-sort pass 2. atomicAdd hands out provably-unique slots within
// each bin; after this kernel cursor[i] == end offset of bin i.
__global__ __launch_bounds__(256) void reorder_kernel(
    const int* __restrict__ src, const int* __restrict__ dst,
    int* __restrict__ cursor, int* __restrict__ sorted_src) {
  int e = blockIdx.x * blockDim.x + threadIdx.x;
  if (e < N_EDGES) {
    int pos = atomicAdd(&cursor[dst[e]], 1);
    sorted_src[pos] = src[e];
  }
}

// ---------------------------------------------------------------------------
// K4: fused gather + mean + GEMV + colsum. One dst row per wave.
// Lane decomposition: es = lane>>4 (edge subgroup), q = lane&15 (row quadrant).
// 4 edges concurrently in flight, each row read as 16 x float4 (256 B).
// All shuffles are executed by all 64 lanes (uniform loop bounds); only the
// accumulate is predicated.
__global__ __launch_bounds__(256) void gather_h(
    const float* __restrict__ x,
    const float* __restrict__ Ww,   // [64][128]
    const float* __restrict__ Wb,   // [64]
    const int*   __restrict__ cursor,      // end offsets after reorder
    const int*   __restrict__ sorted_src,
    float* __restrict__ h,
    float* __restrict__ colsum) {
  __shared__ float Wt[2 * DIM][NCLS + 1];  // Wt[k][c] = Ww[c*128+k]; stride 65
  __shared__ float colred[4][64];

  const int tid = threadIdx.x;
  for (int idx = tid; idx < NCLS * 2 * DIM; idx += 256) {
    int c = idx >> 7, k = idx & 127;
    Wt[k][c] = Ww[idx];
  }
  __syncthreads();

  const int wv   = tid >> 6;
  const int lane = tid & 63;
  const int es   = lane >> 4;
  const int q    = lane & 15;
  const int waveId = blockIdx.x * 4 + wv;
  const int tw     = gridDim.x * 4;
  const float bias = Wb[lane];
  const float4* x4 = reinterpret_cast<const float4*>(x);

  float4 colacc = make_float4(0.f, 0.f, 0.f, 0.f);

  for (int r = waveId; r < N_DSTC; r += tw) {
    int beg = (r == 0) ? 0 : cursor[r - 1];
    int end = cursor[r];
    int cnt = end - beg;

    float4 a = make_float4(0.f, 0.f, 0.f, 0.f);
    for (int base = 0; base < cnt; base += 64) {
      int rem = cnt - base;
      int mm  = rem < 64 ? rem : 64;
      int idxv = (lane < rem) ? sorted_src[beg + base + lane] : 0;
      int nIt = (mm + 3) >> 2;
      for (int jj = 0; jj < nIt; ++jj) {
        int j = (jj << 2) + es;            // this subgroup's edge slot
        int sIdx = __shfl(idxv, j & 63, 64);  // uniform execution; j <= 63
        if (j < mm) {
          float4 v = x4[(long long)sIdx * 16 + q];
          a.x += v.x; a.y += v.y; a.z += v.z; a.w += v.w;
        }
      }
    }
    // reduce across the 4 edge subgroups (all lanes end with full quadrant sum)
    a.x += __shfl_xor(a.x, 16, 64); a.y += __shfl_xor(a.y, 16, 64);
    a.z += __shfl_xor(a.z, 16, 64); a.w += __shfl_xor(a.w, 16, 64);
    a.x += __shfl_xor(a.x, 32, 64); a.y += __shfl_xor(a.y, 32, 64);
    a.z += __shfl_xor(a.z, 32, 64); a.w += __shfl_xor(a.w, 32, 64);

    float inv = 1.0f / fmaxf((float)cnt, 1.0f);
    float4 ym = make_float4(a.x * inv, a.y * inv, a.z * inv, a.w * inv);

    // x_dst row quadrant (same 256B row for whole wave -> coalesces)
    float4 xv = x4[(long long)r * 16 + q];

    if (es == 0) {  // one copy per column for the column-sum
      colacc.x += ym.x; colacc.y += ym.y; colacc.z += ym.z; colacc.w += ym.w;
    }

    // GEMV: h[r][lane] = bias + sum_k x[k]*Wt[k][lane] + ym[k]*Wt[64+k][lane]
    float hacc = bias;
    #pragma unroll
    for (int k = 0; k < DIM; ++k) {
      const int sl = k >> 2;  // source lane (es==0 lane holding quadrant k>>2)
      float fx = __shfl((k & 3) == 0 ? xv.x : (k & 3) == 1 ? xv.y :
                        (k & 3) == 2 ? xv.z : xv.w, sl, 64);
      float fy = __shfl((k & 3) == 0 ? ym.x : (k & 3) == 1 ? ym.y :
                        (k & 3) == 2 ? ym.z : ym.w, sl, 64);
      hacc = fmaf(fx, Wt[k][lane], hacc);
      hacc = fmaf(fy, Wt[DIM + k][lane], hacc);
    }
    h[(long long)r * NCLS + lane] = hacc;
  }

  if (es == 0) {  // lane q owns columns 4q..4q+3
    colred[wv][q * 4 + 0] = colacc.x;
    colred[wv][q * 4 + 1] = colacc.y;
    colred[wv][q * 4 + 2] = colacc.z;
    colred[wv][q * 4 + 3] = colacc.w;
  }
  __syncthreads();
  if (tid < 64) {
    float s = colred[0][tid] + colred[1][tid] + colred[2][tid] + colred[3][tid];
    atomicAdd(&colsum[tid], s);
  }
}

// ---------------------------------------------------------------------------
// K5: reg partial sums. One wave per x row, lane j owns column j.
__global__ __launch_bounds__(256) void reg_kernel(
    const float* __restrict__ x,
    const float* __restrict__ u_sum,
    const float* __restrict__ colsum,
    float* __restrict__ regacc) {
  const int tid  = threadIdx.x;
  const int wv   = tid >> 6;
  const int lane = tid & 63;
  const int waveId     = blockIdx.x * 4 + wv;
  const int totalWaves = gridDim.x * 4;
  const float inv_nd = 1.0f / (float)N_DSTC;
  const float mx = colsum[lane] * inv_nd;   // mean_x[lane]

  float acc = 0.0f;
  for (int r = waveId; r < N_SRC; r += totalWaves) {
    float u  = u_sum[r] * inv_nd;           // broadcast
    float xv = x[(long long)r * DIM + lane];
    float d  = fmaf(u, xv, -mx);
    acc = fmaf(d, d, acc);
  }
  #pragma unroll
  for (int off = 32; off > 0; off >>= 1)
    acc += __shfl_down(acc, off, 64);
  if (lane == 0) atomicAdd(regacc, acc);
}

// ---------------------------------------------------------------------------
__global__ void finalize(const float* __restrict__ regacc,
                         float* __restrict__ out_scalar) {
  out_scalar[0] = regacc[0] * (1.0f / ((float)N_SRC * (float)NCLS));
}

// ---------------------------------------------------------------------------
extern "C" void kernel_launch(void* const* d_in, const int* in_sizes, int n_in,
                              void* d_out, int out_size, void* d_ws, size_t ws_size,
                              hipStream_t stream) {
  const float* x     = (const float*)d_in[0];
  // d_in[1] = w : dead (only ones_like(w) is used)
  const float* u_sum = (const float*)d_in[2];
  const float* Ww    = (const float*)d_in[3];
  const float* Wb    = (const float*)d_in[4];
  const int*   src   = (const int*)d_in[5];
  const int*   dst   = (const int*)d_in[6];

  float* out = (float*)d_out;
  int*   wsI = (int*)d_ws;

  int*   hist       = wsI;                       // 50000
  float* colsum     = (float*)(wsI + N_DSTC);    // 64
  float* regacc     = colsum + 64;               // 1
  int*   cursor     = (int*)(regacc + 1);        // 50000
  int*   sorted_src = cursor + N_DSTC;           // 1,000,000

  // zero hist + colsum + regacc (contiguous front region)
  hipMemsetAsync(d_ws, 0, (size_t)(N_DSTC + 64 + 1) * sizeof(int), stream);

  hist_kernel<<<(N_EDGES + 255) / 256, 256, 0, stream>>>(dst, hist);
  scan_kernel<<<1, 1024, 0, stream>>>(hist, cursor);
  reorder_kernel<<<(N_EDGES + 255) / 256, 256, 0, stream>>>(src, dst, cursor, sorted_src);
  gather_h<<<2048, 256, 0, stream>>>(x, Ww, Wb, cursor, sorted_src, out, colsum);
  reg_kernel<<<2048, 256, 0, stream>>>(x, u_sum, colsum, regacc);
  finalize<<<1, 1, 0, stream>>>(regacc, out + (size_t)N_DSTC * NCLS);
}